// Round 11
// baseline (1611.566 us; speedup 1.0000x reference)
//
#include <hip/hip_runtime.h>
#include <hip/hip_cooperative_groups.h>
#include <hip/hip_bf16.h>

namespace cg = cooperative_groups;

#define NPTS 256
#define NB   4
#define KNN  27
#define EPSV 1e-5f

typedef unsigned short u16;
typedef _Float16 f16;
typedef __attribute__((ext_vector_type(8))) _Float16 f16x8;
typedef __attribute__((ext_vector_type(4))) float f32x4;

// ---------------- workspace layout (bytes); ws = 256 MiB ----------------
#define OFF_IDX    0           // idxT [k][pt]: 27*1024*4 = 110592
#define OFF_XYZ    131072      // 4*256*32*2 = 65536   f16 [b][n][32]
#define OFF_A0     262144      // 128*32*2    = 8192
#define OFF_A1     270336      // 384*96*2    = 73728
#define OFF_A2     344064      // 1536*384*2  = 1179648
#define OFF_A3     1523712     // 6144*1536*2 = 18874368
#define OFF_A4     20398080    // 256*8160*2  = 4177920
#define OFF_PQ     24576000    // f16 partial planes, up to 4*4*6144*256*2
#define OFF_XC     62324736    // 4*256*8160*2 = 16711680  f16 [b][n][8160]
#define OFF_Y      79036416    // f16: 15*4*256*256*2 = 7864320
// end ~87 MB

__device__ __forceinline__ float f16_lo(unsigned w) {
    union { u16 u; f16 h; } c; c.u = (u16)(w & 0xffffu); return (float)c.h;
}
__device__ __forceinline__ float f16_hi(unsigned w) {
    union { u16 u; f16 h; } c; c.u = (u16)(w >> 16); return (float)c.h;
}
__device__ __forceinline__ u16 f16_bits(float f) {
    union { f16 h; u16 u; } c; c.h = (f16)f; return c.u;
}
__device__ __forceinline__ float f16_val(u16 u) {
    union { u16 u; f16 h; } c; c.u = u; return (float)c.h;
}

__device__ __forceinline__ float dist3_nocontract(float ax, float ay, float az,
                                                  float bx, float by, float bz) {
#pragma clang fp contract(off)
    float dx = bx - ax, dy = by - ay, dz = bz - az;
    float s = dx * dx;
    s = s + dy * dy;
    s = s + dz * dz;
    return s;
}

// ======================= the mega-kernel ====================================
// 256 blocks x 1024 threads, cooperative. Phases separated by grid.sync():
//   P0: kNN (blocks 0..63, 1 wave/point) + weight prep (grid-stride)
//   per layer: gemm (virtual 256-thr tile groups) | gather (4ch/block-pass)
//   final gemm (split-K=15) | final_bn
__global__ __launch_bounds__(1024) void mega(
    const float* __restrict__ x,
    const float* __restrict__ w0, const float* __restrict__ g0, const float* __restrict__ b0,
    const float* __restrict__ w1, const float* __restrict__ g1, const float* __restrict__ b1,
    const float* __restrict__ w2, const float* __restrict__ g2, const float* __restrict__ b2,
    const float* __restrict__ w3, const float* __restrict__ g3, const float* __restrict__ b3,
    const float* __restrict__ w4, const float* __restrict__ g4, const float* __restrict__ b4,
    float* __restrict__ out, char* __restrict__ ws)
{
    cg::grid_group grid = cg::this_grid();
    __shared__ __align__(16) char smem[81920];

    const int t = threadIdx.x;
    const int bx = blockIdx.x;
    const int sub = t >> 8;         // 0..3 virtual 256-thread group
    const int t256 = t & 255;
    const int wv = t >> 6;          // 0..15
    const int lane = t & 63;

    int* idxT = (int*)(ws + OFF_IDX);
    f16* xyz = (f16*)(ws + OFF_XYZ);
    u16* PQ  = (u16*)(ws + OFF_PQ);
    u16* xc  = (u16*)(ws + OFF_XC);
    u16* y   = (u16*)(ws + OFF_Y);
    const f16* xcf = (const f16*)xc;

    // ---------------- P0a: kNN (blocks 0..63, one wave per point) ----------
    if (bx < 64) {
        int pt = bx * 16 + wv;          // 0..1023
        int pb = pt >> 8, pn = pt & 255;
        float xp0 = x[pt * 3 + 0];
        float xp1 = x[pt * 3 + 1];
        float xp2 = x[pt * 3 + 2];
        if (lane < 32) {
            float v = (lane < 3) ? x[pt * 3 + lane] : 0.f;
            xyz[((long)pb * NPTS + pn) * 32 + lane] = (f16)v;
        }
        unsigned long long key[4];
#pragma unroll
        for (int u = 0; u < 4; ++u) {
            int j = lane + 64 * u;
            int gj = pb * NPTS + j;
            float d = dist3_nocontract(xp0, xp1, xp2,
                                       x[gj * 3 + 0], x[gj * 3 + 1], x[gj * 3 + 2]);
            key[u] = ((unsigned long long)__float_as_uint(d) << 32) | (unsigned int)j;
        }
        for (int r = 0; r < KNN; ++r) {
            unsigned long long m = key[0];
            m = key[1] < m ? key[1] : m;
            m = key[2] < m ? key[2] : m;
            m = key[3] < m ? key[3] : m;
#pragma unroll
            for (int off = 32; off; off >>= 1) {
                unsigned long long o = __shfl_xor(m, off);
                m = o < m ? o : m;
            }
            if (lane == 0) idxT[r * 1024 + pt] = (int)(m & 0xffffffffu);
#pragma unroll
            for (int u = 0; u < 4; ++u)
                if (key[u] == m) key[u] = ~0ULL;
        }
    }

    // ---------------- P0b: weight prep (grid-stride over 9216 chunks) ------
    for (int c = bx * 4 + sub; c < 9216; c += 1024) {
        const float* w;
        int r, cbase = 0, M, Co, K, Kpad, mode;
        long offA;
        if (c < 128)      { w = w0; r = c;        M = 96;   Co = 48;   K = 3;    Kpad = 32;   mode = 0; offA = OFF_A0; }
        else if (c < 512) { w = w1; r = c - 128;  M = 384;  Co = 192;  K = 96;   Kpad = 96;   mode = 0; offA = OFF_A1; }
        else if (c < 2048){ w = w2; r = c - 512;  M = 1536; Co = 768;  K = 384;  Kpad = 384;  mode = 0; offA = OFF_A2; }
        else if (c < 8192){ w = w3; r = c - 2048; M = 6144; Co = 3072; K = 1536; Kpad = 1536; mode = 0; offA = OFF_A3; }
        else { int loc = c - 8192; w = w4; r = loc >> 2; cbase = (loc & 3) * 2048;
               M = 256; Co = 0; K = 8160; Kpad = 8160; mode = 1; offA = OFF_A4; }
        int c0 = cbase + t256 * 8;
        if (c0 < Kpad) {
            f16* A = (f16*)(ws + offA);
            f16x8 hv;
#pragma unroll
            for (int j = 0; j < 8; ++j) {
                int cc = c0 + j;
                float a = 0.f;
                if (cc < K && r < M) {
                    if (mode == 1) a = w[(long)r * K + cc];
                    else if (r < Co) a = w[(long)r * (2 * K) + cc];
                    else {
                        long base = (long)(r - Co) * (2 * K);
                        a = w[base + K + cc] - w[base + cc];
                    }
                }
                hv[j] = (f16)a;
            }
            *(f16x8*)&A[(long)r * Kpad + c0] = hv;
        }
    }

    // ---------------- phase lambdas ----------------------------------------
    // gemm: virtual tile vt = sub*256 + bx (block-major for even CU use).
    // All tiles in a layer share the same K-trip count -> barriers uniform.
    auto gemm_phase = [&](const f16* A, const f16* B, u16* O,
                          int M, int K, int ldF, long bsF, int nsp, int kchunk) {
        int Mpad = (M + 127) & ~127;
        int nm = Mpad >> 7;
        int ntiles = nm * 2 * NB * nsp;
        int vt = sub * 256 + bx;
        bool valid = vt < ntiles;
        int tile = valid ? vt : 0;
        int mi = tile % nm;
        int r = tile / nm;
        int n0 = (r & 1) << 7; r >>= 1;
        int b = r & 3;
        int slice = r >> 2;
        int m0 = mi << 7;
        int kstart = slice * kchunk;

        u16 (*sA)[40] = (u16 (*)[40])(smem + sub * 20480);
        u16 (*sB)[40] = (u16 (*)[40])(smem + sub * 20480 + 10240);

        const f16* pB = B + (long)b * bsF;
        u16* Ob = O + (long)slice * ((long)NB * M * NPTS) + (long)b * ((long)M * NPTS);

        int lane2 = t256 & 63, wid2 = t256 >> 6;
        int wm = (wid2 >> 1) * 64, wn = (wid2 & 1) * 64;
        int lrow = lane2 & 15, quad = lane2 >> 4;
        int srow = t256 >> 1, sk = (t256 & 1) * 16;

        const f16* gA = A + (long)(m0 + srow) * K + sk;
        const f16* gB = pB + (long)(n0 + srow) * ldF + sk;

        f32x4 acc[4][4] = {};
        int niter = kchunk >> 5;
        for (int it = 0; it < niter; ++it) {
            int kk = kstart + (it << 5);
            f16x8 a0 = *(const f16x8*)(gA + kk);
            f16x8 a1 = *(const f16x8*)(gA + kk + 8);
            f16x8 b0 = *(const f16x8*)(gB + kk);
            f16x8 b1 = *(const f16x8*)(gB + kk + 8);
            __syncthreads();
            *(f16x8*)&sA[srow][sk] = a0;
            *(f16x8*)&sA[srow][sk + 8] = a1;
            *(f16x8*)&sB[srow][sk] = b0;
            *(f16x8*)&sB[srow][sk + 8] = b1;
            __syncthreads();
            f16x8 fb[4];
#pragma unroll
            for (int nt = 0; nt < 4; ++nt)
                fb[nt] = *(const f16x8*)&sB[wn + nt * 16 + lrow][quad * 8];
#pragma unroll
            for (int mt = 0; mt < 4; ++mt) {
                f16x8 fa = *(const f16x8*)&sA[wm + mt * 16 + lrow][quad * 8];
#pragma unroll
                for (int nt = 0; nt < 4; ++nt)
                    acc[mt][nt] = __builtin_amdgcn_mfma_f32_16x16x32_f16(fa, fb[nt], acc[mt][nt], 0, 0, 0);
            }
        }
        if (valid) {
#pragma unroll
            for (int mt = 0; mt < 4; ++mt)
#pragma unroll
                for (int nt = 0; nt < 4; ++nt) {
                    int C = n0 + wn + nt * 16 + lrow;
                    int Rb = m0 + wm + mt * 16 + quad * 4;
#pragma unroll
                    for (int rr = 0; rr < 4; ++rr) {
                        int R = Rb + rr;
                        if (R < M) Ob[(long)R * NPTS + C] = f16_bits(acc[mt][nt][rr]);
                    }
                }
        }
    };

    // gather: block handles 4 channels per pass; thread <-> (b,n).
    auto gather_phase = [&](int Co, int offc, int nsp,
                            const float* gp, const float* bp) {
        long pstride = (long)NB * 2 * Co * NPTS;
        int ngroups = Co >> 2;
        int npassG = (ngroups + 255) >> 8;
        uint2* p2 = (uint2*)smem;                      // [1024] packed f16x4 P
        uint2* vls = (uint2*)(smem + 8192);            // [512] val for flat b 0,1
        float* red = (float*)(smem + 12288);           // [16][8]
        float* sctt = (float*)(smem + 12288 + 512);    // [8]
        int pb = t >> 8, pn = t & 255;
        const float cnt = (float)(NB * NPTS * KNN);

        for (int pass = 0; pass < npassG; ++pass) {
            int gI = pass * 256 + bx;
            bool act = gI < ngroups;
            int o0 = (act ? gI : 0) << 2;
            long base_p = ((long)pb * 2 * Co + o0) * NPTS + pn;
            long base_q = base_p + (long)Co * NPTS;

            float q[4];
            u16 ph[4];
#pragma unroll
            for (int c = 0; c < 4; ++c) {
                float pv = 0.f, qv = 0.f;
                for (int sp = 0; sp < nsp; ++sp) {
                    pv += f16_val(PQ[sp * pstride + base_p + c * NPTS]);
                    qv += f16_val(PQ[sp * pstride + base_q + c * NPTS]);
                }
                ph[c] = f16_bits(pv);
                q[c] = qv;
            }
            uint2 pk;
            pk.x = (unsigned)ph[0] | ((unsigned)ph[1] << 16);
            pk.y = (unsigned)ph[2] | ((unsigned)ph[3] << 16);
            p2[t] = pk;
            __syncthreads();

            float s[4] = {}, ssq[4] = {};
            float mx[4], mn[4];
#pragma unroll
            for (int c = 0; c < 4; ++c) { mx[c] = -__builtin_inff(); mn[c] = __builtin_inff(); }
#pragma unroll 1
            for (int k = 0; k < KNN; ++k) {
                int j = idxT[k * 1024 + t];
                uint2 w = p2[pb * 256 + j];
                float h0 = f16_lo(w.x) + q[0];
                float h1 = f16_hi(w.x) + q[1];
                float h2 = f16_lo(w.y) + q[2];
                float h3 = f16_hi(w.y) + q[3];
                s[0] += h0; ssq[0] += h0 * h0; mx[0] = fmaxf(mx[0], h0); mn[0] = fminf(mn[0], h0);
                s[1] += h1; ssq[1] += h1 * h1; mx[1] = fmaxf(mx[1], h1); mn[1] = fminf(mn[1], h1);
                s[2] += h2; ssq[2] += h2 * h2; mx[2] = fmaxf(mx[2], h2); mn[2] = fminf(mn[2], h2);
                s[3] += h3; ssq[3] += h3 * h3; mx[3] = fmaxf(mx[3], h3); mn[3] = fminf(mn[3], h3);
            }
#pragma unroll
            for (int c = 0; c < 4; ++c)
#pragma unroll
                for (int off = 32; off; off >>= 1) {
                    s[c] += __shfl_xor(s[c], off);
                    ssq[c] += __shfl_xor(ssq[c], off);
                }
            if (lane == 0) {
#pragma unroll
                for (int c = 0; c < 4; ++c) {
                    red[wv * 8 + c] = s[c];
                    red[wv * 8 + 4 + c] = ssq[c];
                }
            }
            __syncthreads();
            if (t < 8) {
                float a = 0.f;
#pragma unroll
                for (int w8 = 0; w8 < 16; ++w8) a += red[w8 * 8 + t];
                red[t] = a;
            }
            __syncthreads();
            if (t < 4) {
                float mean = red[t] / cnt;
                float var = red[4 + t] / cnt - mean * mean;
                float sc = gp[o0 + t] * (1.0f / sqrtf(var + EPSV));
                sctt[t] = sc;
                sctt[4 + t] = bp[o0 + t] - mean * sc;
            }
            __syncthreads();

            u16 vh[4];
#pragma unroll
            for (int c = 0; c < 4; ++c) {
                float sc = sctt[c], tt = sctt[4 + c];
                float e = (sc >= 0.f) ? mx[c] : mn[c];
                float z = sc * e + tt;
                z = z >= 0.f ? z : 0.2f * z;
                vh[c] = f16_bits(z);
            }
            uint2 vk;
            vk.x = (unsigned)vh[0] | ((unsigned)vh[1] << 16);
            vk.y = (unsigned)vh[2] | ((unsigned)vh[3] << 16);
            if (pb < 2) vls[pb * 256 + pn] = vk;
            if (act) *(uint2*)&xc[(long)t * 8160 + offc + o0] = vk;
            __syncthreads();

            uint2 va = vls[pn], vb = vls[256 + pn];
            u16 th[4];
            th[0] = f16_bits(0.5f * (f16_lo(va.x) + f16_lo(vb.x)));
            th[1] = f16_bits(0.5f * (f16_hi(va.x) + f16_hi(vb.x)));
            th[2] = f16_bits(0.5f * (f16_lo(va.y) + f16_lo(vb.y)));
            th[3] = f16_bits(0.5f * (f16_hi(va.y) + f16_hi(vb.y)));
            uint2 tk2;
            tk2.x = (unsigned)th[0] | ((unsigned)th[1] << 16);
            tk2.y = (unsigned)th[2] | ((unsigned)th[3] << 16);
            if (act) *(uint2*)&xc[(long)t * 8160 + offc + Co + o0] = tk2;
            __syncthreads();   // protect p2/vls reuse in next pass
        }
    };

    // ---------------- phase sequence ---------------------------------------
    const f16* A0 = (const f16*)(ws + OFF_A0);
    const f16* A1 = (const f16*)(ws + OFF_A1);
    const f16* A2 = (const f16*)(ws + OFF_A2);
    const f16* A3 = (const f16*)(ws + OFF_A3);
    const f16* A4 = (const f16*)(ws + OFF_A4);

    __threadfence(); grid.sync();

    gemm_phase(A0, (const f16*)xyz, PQ, 96, 32, 32, (long)NPTS * 32, 1, 32);
    __threadfence(); grid.sync();
    gather_phase(48, 0, 1, g0, b0);
    __threadfence(); grid.sync();

    gemm_phase(A1, xcf + 0, PQ, 384, 96, 8160, (long)NPTS * 8160, 3, 32);
    __threadfence(); grid.sync();
    gather_phase(192, 96, 3, g1, b1);
    __threadfence(); grid.sync();

    gemm_phase(A2, xcf + 96, PQ, 1536, 384, 8160, (long)NPTS * 8160, 4, 96);
    __threadfence(); grid.sync();
    gather_phase(768, 480, 4, g2, b2);
    __threadfence(); grid.sync();

    gemm_phase(A3, xcf + 480, PQ, 6144, 1536, 8160, (long)NPTS * 8160, 2, 768);
    __threadfence(); grid.sync();
    gather_phase(3072, 2016, 2, g3, b3);
    __threadfence(); grid.sync();

    gemm_phase(A4, xcf, y, 256, 8160, 8160, (long)NPTS * 8160, 15, 544);
    __threadfence(); grid.sync();

    // ---------------- final BN + lrelu -> fp32 out (sums 15 f16 y planes) --
    {
        float* red = (float*)smem;
        int o = bx;
        float v[4];
        float s = 0.f, ssum = 0.f;
        if (t < 256) {
#pragma unroll
            for (int b = 0; b < 4; ++b) {
                float acc = 0.f;
#pragma unroll
                for (int sp = 0; sp < 15; ++sp)
                    acc += f16_val(y[sp * 262144 + b * 65536 + o * 256 + t]);
                v[b] = acc;
                s += acc;
                ssum += acc * acc;
            }
#pragma unroll
            for (int off = 32; off; off >>= 1) {
                s += __shfl_xor(s, off);
                ssum += __shfl_xor(ssum, off);
            }
            if ((t & 63) == 0) {
                red[t >> 6] = s;
                red[4 + (t >> 6)] = ssum;
            }
        }
        __syncthreads();
        if (t < 256) {
            float S = (red[0] + red[1]) + (red[2] + red[3]);
            float SS = (red[4] + red[5]) + (red[6] + red[7]);
            float mean = S / 1024.f;
            float var = SS / 1024.f - mean * mean;
            float sc = g4[o] * (1.0f / sqrtf(var + EPSV));
            float tt = b4[o] - mean * sc;
#pragma unroll
            for (int b = 0; b < 4; ++b) {
                float z = sc * v[b] + tt;
                z = z >= 0.f ? z : 0.2f * z;
                out[(long)b * 65536 + o * 256 + t] = z;
            }
        }
    }
}

// ---------------- launch ----------------
extern "C" void kernel_launch(void* const* d_in, const int* in_sizes, int n_in,
                              void* d_out, int out_size, void* d_ws, size_t ws_size,
                              hipStream_t stream) {
    const float* x = (const float*)d_in[0];
    const float* w0 = (const float*)d_in[1];
    const float* g0 = (const float*)d_in[2];
    const float* b0 = (const float*)d_in[3];
    const float* w1 = (const float*)d_in[4];
    const float* g1 = (const float*)d_in[5];
    const float* b1 = (const float*)d_in[6];
    const float* w2 = (const float*)d_in[7];
    const float* g2 = (const float*)d_in[8];
    const float* b2 = (const float*)d_in[9];
    const float* w3 = (const float*)d_in[10];
    const float* g3 = (const float*)d_in[11];
    const float* b3 = (const float*)d_in[12];
    const float* w4 = (const float*)d_in[13];
    const float* g4 = (const float*)d_in[14];
    const float* b4 = (const float*)d_in[15];
    float* out = (float*)d_out;
    char* ws = (char*)d_ws;

    void* args[] = {
        (void*)&x,
        (void*)&w0, (void*)&g0, (void*)&b0,
        (void*)&w1, (void*)&g1, (void*)&b1,
        (void*)&w2, (void*)&g2, (void*)&b2,
        (void*)&w3, (void*)&g3, (void*)&b3,
        (void*)&w4, (void*)&g4, (void*)&b4,
        (void*)&out, (void*)&ws,
    };
    hipLaunchCooperativeKernel((void*)mega, dim3(256), dim3(1024), args, 0, stream);
}